// Round 5
// baseline (604.179 us; speedup 1.0000x reference)
//
#include <hip/hip_runtime.h>
#include <hip/hip_bf16.h>

#define NNODES 65536
#define NEDGES 262144
#define BATCH  64
#define HDIM   256
#define NSLAB  8
#define NPB    128          // nodes per k_gemm block -> 512 blocks

// ---------------------------------------------------------------------------
// K1: per-node u[n] = Wf[0:H] . x[n],  v[n] = Wf[H:2H] . x[n]
//     one wave per node, float4 per lane (64*16B = 1KB coalesced row read)
// ---------------------------------------------------------------------------
__global__ __launch_bounds__(256) void k_uv(
    const float* __restrict__ hidden, const int* __restrict__ node_idx,
    const float* __restrict__ Wf, float* __restrict__ u, float* __restrict__ v) {
  int gw   = (blockIdx.x * 256 + threadIdx.x) >> 6;   // global wave = node
  int lane = threadIdx.x & 63;
  if (gw >= NNODES) return;
  const float4* xr = (const float4*)(hidden + (size_t)node_idx[gw] * HDIM);
  float4 xv = xr[lane];
  float4 wa = ((const float4*)Wf)[lane];
  float4 wb = ((const float4*)Wf)[64 + lane];
  float su = xv.x*wa.x + xv.y*wa.y + xv.z*wa.z + xv.w*wa.w;
  float sv = xv.x*wb.x + xv.y*wb.y + xv.z*wb.z + xv.w*wb.w;
  #pragma unroll
  for (int off = 32; off > 0; off >>= 1) {
    su += __shfl_down(su, off);
    sv += __shfl_down(sv, off);
  }
  if (lane == 0) { u[gw] = su; v[gw] = sv; }
}

// ---------------------------------------------------------------------------
// K2: per-edge filter weight w_e = sigmoid(u[row]+v[col]+bf); deg[col] += w_e
// ---------------------------------------------------------------------------
__global__ __launch_bounds__(256) void k_edge_w(
    const int* __restrict__ ei, const float* __restrict__ u,
    const float* __restrict__ v, const float* __restrict__ bf,
    float* __restrict__ wbuf, float* __restrict__ deg) {
  int e = blockIdx.x * 256 + threadIdx.x;
  if (e >= NEDGES) return;
  int r = ei[e], c = ei[NEDGES + e];
  float t = u[r] + v[c] + bf[0];
  float w = 1.0f / (1.0f + __expf(-t));
  wbuf[e] = w;
  unsafeAtomicAdd(&deg[c], w);            // random addrs, ~4/address: fine
}

// ---------------------------------------------------------------------------
// K3: dis[n] = rsqrt(deg[n]+1); self-loop weight into t. NO atomics.
// ---------------------------------------------------------------------------
__global__ __launch_bounds__(256) void k_dis(
    const int* __restrict__ node_batch, const float* __restrict__ deg,
    float* __restrict__ dis, float* __restrict__ t) {
  int n = blockIdx.x * 256 + threadIdx.x;
  if (n >= NNODES) return;
  float dn = rsqrtf(deg[n] + 1.0f);
  dis[n] = dn;
  t[(size_t)n * BATCH + node_batch[n]] = dn * dn;
}

// ---------------------------------------------------------------------------
// K3b: counts via binary search on the SORTED node_batch (64 threads total).
// ---------------------------------------------------------------------------
__device__ __forceinline__ int lower_bound_batch(const int* nb, int key) {
  int lo = 0, hi = NNODES;
  while (lo < hi) {
    int mid = (lo + hi) >> 1;
    if (nb[mid] < key) lo = mid + 1; else hi = mid;
  }
  return lo;
}

__global__ __launch_bounds__(64) void k_cnt(
    const int* __restrict__ node_batch, int* __restrict__ cnt) {
  int b = threadIdx.x;   // 0..63
  int s0 = lower_bound_batch(node_batch, b);
  int s1 = lower_bound_batch(node_batch, b + 1);
  cnt[b] = s1 - s0;
}

// ---------------------------------------------------------------------------
// K4: scatter edge coefficients into t[row][batch[col]] (thread-per-edge).
// ---------------------------------------------------------------------------
__global__ __launch_bounds__(256) void k_t(
    const int* __restrict__ ei, const int* __restrict__ node_batch,
    const float* __restrict__ wbuf, const float* __restrict__ dis,
    float* __restrict__ t) {
  int e = blockIdx.x * 256 + threadIdx.x;
  if (e >= NEDGES) return;
  int r = ei[e], c = ei[NEDGES + e];
  float coeff = dis[r] * wbuf[e] * dis[c];
  int b = node_batch[c];
  unsafeAtomicAdd(&t[(size_t)r * BATCH + b], coeff);
}

// ---------------------------------------------------------------------------
// K5: partT[j][b] += sum_n t[n][b] * x[n][j]
//     lane = j-quad (coalesced 1KB x-row load per wave-instr);
//     wave w covers b in [w*16, w*16+16); t broadcast via v_readlane (SGPR).
//     Depth-2 software pipeline on the node_idx -> x-row gather chain.
//     Flush into 8 partial slabs (64 RMW/address instead of 512).
// ---------------------------------------------------------------------------
__global__ __launch_bounds__(256) void k_gemm(
    const float* __restrict__ hidden, const int* __restrict__ node_idx,
    const float* __restrict__ t, float* __restrict__ part) {
  int lane = threadIdx.x & 63;              // j-quad: j = 4*lane+k
  int w    = threadIdx.x >> 6;              // 0..3 -> b base w*16
  int n0   = blockIdx.x * NPB;
  float acc[16][4] = {{0.f}};

  // prologue: x/t for i=0,1 in flight; node index for i=2 loaded
  int  nidA = node_idx[n0];
  int  nidB = node_idx[n0 + 1];
  int  nid2 = node_idx[n0 + 2];
  float  tv  = t[(size_t)n0 * BATCH + lane];
  float  tv1 = t[(size_t)(n0 + 1) * BATCH + lane];
  float4 xv  = *((const float4*)(hidden + (size_t)nidA * HDIM) + lane);
  float4 xv1 = *((const float4*)(hidden + (size_t)nidB * HDIM) + lane);

  #pragma unroll 2
  for (int i = 0; i < NPB; ++i) {
    int ip2 = min(i + 2, NPB - 1);
    int ip3 = min(i + 3, NPB - 1);
    // issue prefetches for i+2 (results land 2 iterations from now)
    float  tv2 = t[(size_t)(n0 + ip2) * BATCH + lane];
    float4 xv2 = *((const float4*)(hidden + (size_t)nid2 * HDIM) + lane);
    int  nid3  = node_idx[n0 + ip3];
    // compute on iteration i's data (loaded 2 iterations ago)
    #pragma unroll
    for (int bi = 0; bi < 16; ++bi) {
      float tb = __int_as_float(
          __builtin_amdgcn_readlane(__float_as_int(tv), w * 16 + bi));
      acc[bi][0] = fmaf(tb, xv.x, acc[bi][0]);
      acc[bi][1] = fmaf(tb, xv.y, acc[bi][1]);
      acc[bi][2] = fmaf(tb, xv.z, acc[bi][2]);
      acc[bi][3] = fmaf(tb, xv.w, acc[bi][3]);
    }
    tv = tv1; tv1 = tv2; xv = xv1; xv1 = xv2; nid2 = nid3;
  }

  float* myp = part + (size_t)(blockIdx.x & (NSLAB - 1)) * (HDIM * BATCH);
  #pragma unroll
  for (int bi = 0; bi < 16; ++bi) {
    #pragma unroll
    for (int k = 0; k < 4; ++k)
      unsafeAtomicAdd(&myp[(4 * lane + k) * BATCH + (w * 16 + bi)], acc[bi][k]);
  }
}

// ---------------------------------------------------------------------------
// K5b: sum the 8 slabs -> aggT[j][b]
// ---------------------------------------------------------------------------
__global__ __launch_bounds__(256) void k_reduce(
    const float* __restrict__ part, float* __restrict__ aggT) {
  int i = blockIdx.x * 256 + threadIdx.x;   // 0..16383
  float s = 0.f;
  #pragma unroll
  for (int k = 0; k < NSLAB; ++k) s += part[(size_t)k * (HDIM * BATCH) + i];
  aggT[i] = s;
}

// ---------------------------------------------------------------------------
// K6: one block per batch b.
//     pooled[k] = (Wc[k,:] . agg[b,:]) / cnt[b] + bc[k]
//     out[b][h] = tanh(Wd[h,:] . pooled + bd[h])
// ---------------------------------------------------------------------------
__global__ __launch_bounds__(256) void k_final(
    const float* __restrict__ aggT, const int* __restrict__ cnt,
    const float* __restrict__ Wc, const float* __restrict__ bc,
    const float* __restrict__ Wd, const float* __restrict__ bd,
    float* __restrict__ out) {
  __shared__ float s_in[HDIM];
  __shared__ float s_mid[HDIM];
  int b = blockIdx.x, tid = threadIdx.x;
  s_in[tid] = aggT[(size_t)tid * BATCH + b];   // transpose gather, tiny
  __syncthreads();
  int lane = tid & 63, wid = tid >> 6;
  float inv = 1.0f / fmaxf((float)cnt[b], 1.0f);
  for (int kk = 0; kk < 64; ++kk) {
    int k = wid * 64 + kk;
    float4 wv = ((const float4*)(Wc + (size_t)k * HDIM))[lane];
    float4 av = ((const float4*)s_in)[lane];
    float p = wv.x*av.x + wv.y*av.y + wv.z*av.z + wv.w*av.w;
    #pragma unroll
    for (int off = 32; off > 0; off >>= 1) p += __shfl_down(p, off);
    if (lane == 0) s_mid[k] = p * inv + bc[k];
  }
  __syncthreads();
  for (int kk = 0; kk < 64; ++kk) {
    int k = wid * 64 + kk;
    float4 wv = ((const float4*)(Wd + (size_t)k * HDIM))[lane];
    float4 av = ((const float4*)s_mid)[lane];
    float p = wv.x*av.x + wv.y*av.y + wv.z*av.z + wv.w*av.w;
    #pragma unroll
    for (int off = 32; off > 0; off >>= 1) p += __shfl_down(p, off);
    if (lane == 0) out[b * HDIM + k] = tanhf(p + bd[k]);
  }
}

// ---------------------------------------------------------------------------
extern "C" void kernel_launch(void* const* d_in, const int* in_sizes, int n_in,
                              void* d_out, int out_size, void* d_ws, size_t ws_size,
                              hipStream_t stream) {
  const float* hidden     = (const float*)d_in[0];
  const int*   node_idx   = (const int*)  d_in[1];
  const int*   ei         = (const int*)  d_in[2];
  const int*   node_batch = (const int*)  d_in[3];
  const float* Wf         = (const float*)d_in[4];
  const float* bf         = (const float*)d_in[5];
  const float* Wc         = (const float*)d_in[6];
  const float* bc         = (const float*)d_in[7];
  const float* Wd         = (const float*)d_in[8];
  const float* bd         = (const float*)d_in[9];
  float* out = (float*)d_out;

  // workspace layout (floats). part ALIASES u/v (dead after k_t).
  float* ws   = (float*)d_ws;
  float* t    = ws;                               // 4,194,304
  float* aggT = t + (size_t)NNODES * BATCH;       // 16,384  ([j][b])
  float* deg  = aggT + HDIM * BATCH;              // 65,536
  int*   cnt  = (int*)(deg + NNODES);             // 64
  float* u    = (float*)(cnt + 64);               // 65,536
  float* v    = u + NNODES;                       // 65,536
  float* dis  = v + NNODES;                       // 65,536
  float* wbuf = dis + NNODES;                     // 262,144
  float* part = u;                                // NSLAB*16,384 = 131,072 (fits u+v)

  (void)hipMemsetAsync(t, 0,
      ((size_t)NNODES * BATCH + HDIM * BATCH + NNODES + 64) * sizeof(float),
      stream);

  k_uv    <<<NNODES / 4,   256, 0, stream>>>(hidden, node_idx, Wf, u, v);
  k_edge_w<<<NEDGES / 256, 256, 0, stream>>>(ei, u, v, bf, wbuf, deg);
  k_dis   <<<NNODES / 256, 256, 0, stream>>>(node_batch, deg, dis, t);
  k_cnt   <<<1,            64,  0, stream>>>(node_batch, cnt);
  k_t     <<<NEDGES / 256, 256, 0, stream>>>(ei, node_batch, wbuf, dis, t);
  // u/v/dis/wbuf now dead -> reuse as partial slabs (zeroed first)
  (void)hipMemsetAsync(part, 0, (size_t)NSLAB * HDIM * BATCH * sizeof(float), stream);
  k_gemm  <<<NNODES / NPB, 256, 0, stream>>>(hidden, node_idx, t, part);
  k_reduce<<<HDIM * BATCH / 256, 256, 0, stream>>>(part, aggT);
  k_final <<<BATCH,        256, 0, stream>>>(aggT, cnt, Wc, bc, Wd, bd, out);
}

// Round 6
// 304.723 us; speedup vs baseline: 1.9827x; 1.9827x over previous
//
#include <hip/hip_runtime.h>
#include <hip/hip_bf16.h>

#define NNODES 65536
#define NEDGES 262144
#define BATCH  64
#define HDIM   256
#define NSLAB  8
#define NPB    128          // nodes per k_gemm block -> 512 blocks

// ---------------------------------------------------------------------------
// K1: per-node u[n] = Wf[0:H] . x[n],  v[n] = Wf[H:2H] . x[n]
//     AND write the gathered row to xg[n] (linear) so the big GEMM never
//     has to chase node_idx. One wave per node, float4 per lane.
// ---------------------------------------------------------------------------
__global__ __launch_bounds__(256) void k_uv(
    const float* __restrict__ hidden, const int* __restrict__ node_idx,
    const float* __restrict__ Wf, float* __restrict__ u, float* __restrict__ v,
    float* __restrict__ xg) {
  int gw   = (blockIdx.x * 256 + threadIdx.x) >> 6;   // global wave = node
  int lane = threadIdx.x & 63;
  if (gw >= NNODES) return;
  const float4* xr = (const float4*)(hidden + (size_t)node_idx[gw] * HDIM);
  float4 xv = xr[lane];
  ((float4*)(xg + (size_t)gw * HDIM))[lane] = xv;     // linearized gather
  float4 wa = ((const float4*)Wf)[lane];
  float4 wb = ((const float4*)Wf)[64 + lane];
  float su = xv.x*wa.x + xv.y*wa.y + xv.z*wa.z + xv.w*wa.w;
  float sv = xv.x*wb.x + xv.y*wb.y + xv.z*wb.z + xv.w*wb.w;
  #pragma unroll
  for (int off = 32; off > 0; off >>= 1) {
    su += __shfl_down(su, off);
    sv += __shfl_down(sv, off);
  }
  if (lane == 0) { u[gw] = su; v[gw] = sv; }
}

// ---------------------------------------------------------------------------
// K2: per-edge filter weight w_e = sigmoid(u[row]+v[col]+bf); deg[col] += w_e
// ---------------------------------------------------------------------------
__global__ __launch_bounds__(256) void k_edge_w(
    const int* __restrict__ ei, const float* __restrict__ u,
    const float* __restrict__ v, const float* __restrict__ bf,
    float* __restrict__ wbuf, float* __restrict__ deg) {
  int e = blockIdx.x * 256 + threadIdx.x;
  if (e >= NEDGES) return;
  int r = ei[e], c = ei[NEDGES + e];
  float t = u[r] + v[c] + bf[0];
  float w = 1.0f / (1.0f + __expf(-t));
  wbuf[e] = w;
  unsafeAtomicAdd(&deg[c], w);            // random addrs, ~4/address: fine
}

// ---------------------------------------------------------------------------
// K3: dis[n] = rsqrt(deg[n]+1); self-loop weight into t. NO atomics.
// ---------------------------------------------------------------------------
__global__ __launch_bounds__(256) void k_dis(
    const int* __restrict__ node_batch, const float* __restrict__ deg,
    float* __restrict__ dis, float* __restrict__ t) {
  int n = blockIdx.x * 256 + threadIdx.x;
  if (n >= NNODES) return;
  float dn = rsqrtf(deg[n] + 1.0f);
  dis[n] = dn;
  t[(size_t)n * BATCH + node_batch[n]] = dn * dn;
}

// ---------------------------------------------------------------------------
// K3b: counts via binary search on the SORTED node_batch (64 threads total).
// ---------------------------------------------------------------------------
__device__ __forceinline__ int lower_bound_batch(const int* nb, int key) {
  int lo = 0, hi = NNODES;
  while (lo < hi) {
    int mid = (lo + hi) >> 1;
    if (nb[mid] < key) lo = mid + 1; else hi = mid;
  }
  return lo;
}

__global__ __launch_bounds__(64) void k_cnt(
    const int* __restrict__ node_batch, int* __restrict__ cnt) {
  int b = threadIdx.x;   // 0..63
  int s0 = lower_bound_batch(node_batch, b);
  int s1 = lower_bound_batch(node_batch, b + 1);
  cnt[b] = s1 - s0;
}

// ---------------------------------------------------------------------------
// K4: scatter edge coefficients into t[row][batch[col]] (thread-per-edge).
// ---------------------------------------------------------------------------
__global__ __launch_bounds__(256) void k_t(
    const int* __restrict__ ei, const int* __restrict__ node_batch,
    const float* __restrict__ wbuf, const float* __restrict__ dis,
    float* __restrict__ t) {
  int e = blockIdx.x * 256 + threadIdx.x;
  if (e >= NEDGES) return;
  int r = ei[e], c = ei[NEDGES + e];
  float coeff = dis[r] * wbuf[e] * dis[c];
  int b = node_batch[c];
  unsafeAtomicAdd(&t[(size_t)r * BATCH + b], coeff);
}

// ---------------------------------------------------------------------------
// K5: aggT[j][b] = sum_n t[n][b] * x[n][j]  -- STREAMING (xg is linear).
//     R3's proven mapping: 1024 threads = 16 waves; lane = b; wave w owns
//     disjoint j-quads {w, w+16, w+32, w+48}; acc[4][4] = 16 VGPRs (no
//     spill). All loads linear in n -> no dependent gather chain, the
//     compiler can pipeline freely. Flush: lane-contiguous atomics
//     (256B/instr) into 8 partial slabs (64 RMW/address instead of 512).
// ---------------------------------------------------------------------------
__global__ __launch_bounds__(1024) void k_gemm(
    const float* __restrict__ xg, const float* __restrict__ t,
    float* __restrict__ part) {
  int lane = threadIdx.x & 63;              // = b
  int w    = threadIdx.x >> 6;              // 0..15
  int n0   = blockIdx.x * NPB;
  float acc[4][4] = {{0.f}};
  #pragma unroll 4
  for (int i = 0; i < NPB; ++i) {
    int n = n0 + i;
    float tv = t[(size_t)n * BATCH + lane];
    const float* xr = xg + (size_t)n * HDIM;
    #pragma unroll
    for (int q = 0; q < 4; ++q) {
      float4 xq = *(const float4*)(xr + (w + q * 16) * 4);
      acc[q][0] = fmaf(tv, xq.x, acc[q][0]);
      acc[q][1] = fmaf(tv, xq.y, acc[q][1]);
      acc[q][2] = fmaf(tv, xq.z, acc[q][2]);
      acc[q][3] = fmaf(tv, xq.w, acc[q][3]);
    }
  }
  float* myp = part + (size_t)(blockIdx.x & (NSLAB - 1)) * (HDIM * BATCH);
  #pragma unroll
  for (int q = 0; q < 4; ++q) {
    int j = (w + q * 16) * 4;
    #pragma unroll
    for (int k = 0; k < 4; ++k)
      unsafeAtomicAdd(&myp[(size_t)(j + k) * BATCH + lane], acc[q][k]);
  }
}

// ---------------------------------------------------------------------------
// K5b: sum the 8 slabs -> aggT[j][b]
// ---------------------------------------------------------------------------
__global__ __launch_bounds__(256) void k_reduce(
    const float* __restrict__ part, float* __restrict__ aggT) {
  int i = blockIdx.x * 256 + threadIdx.x;   // 0..16383
  float s = 0.f;
  #pragma unroll
  for (int k = 0; k < NSLAB; ++k) s += part[(size_t)k * (HDIM * BATCH) + i];
  aggT[i] = s;
}

// ---------------------------------------------------------------------------
// K6: one block per batch b.
//     pooled[k] = (Wc[k,:] . agg[b,:]) / cnt[b] + bc[k]
//     out[b][h] = tanh(Wd[h,:] . pooled + bd[h])
// ---------------------------------------------------------------------------
__global__ __launch_bounds__(256) void k_final(
    const float* __restrict__ aggT, const int* __restrict__ cnt,
    const float* __restrict__ Wc, const float* __restrict__ bc,
    const float* __restrict__ Wd, const float* __restrict__ bd,
    float* __restrict__ out) {
  __shared__ float s_in[HDIM];
  __shared__ float s_mid[HDIM];
  int b = blockIdx.x, tid = threadIdx.x;
  s_in[tid] = aggT[(size_t)tid * BATCH + b];   // transpose gather, tiny
  __syncthreads();
  int lane = tid & 63, wid = tid >> 6;
  float inv = 1.0f / fmaxf((float)cnt[b], 1.0f);
  for (int kk = 0; kk < 64; ++kk) {
    int k = wid * 64 + kk;
    float4 wv = ((const float4*)(Wc + (size_t)k * HDIM))[lane];
    float4 av = ((const float4*)s_in)[lane];
    float p = wv.x*av.x + wv.y*av.y + wv.z*av.z + wv.w*av.w;
    #pragma unroll
    for (int off = 32; off > 0; off >>= 1) p += __shfl_down(p, off);
    if (lane == 0) s_mid[k] = p * inv + bc[k];
  }
  __syncthreads();
  for (int kk = 0; kk < 64; ++kk) {
    int k = wid * 64 + kk;
    float4 wv = ((const float4*)(Wd + (size_t)k * HDIM))[lane];
    float4 av = ((const float4*)s_mid)[lane];
    float p = wv.x*av.x + wv.y*av.y + wv.z*av.z + wv.w*av.w;
    #pragma unroll
    for (int off = 32; off > 0; off >>= 1) p += __shfl_down(p, off);
    if (lane == 0) out[b * HDIM + k] = tanhf(p + bd[k]);
  }
}

// ---------------------------------------------------------------------------
extern "C" void kernel_launch(void* const* d_in, const int* in_sizes, int n_in,
                              void* d_out, int out_size, void* d_ws, size_t ws_size,
                              hipStream_t stream) {
  const float* hidden     = (const float*)d_in[0];
  const int*   node_idx   = (const int*)  d_in[1];
  const int*   ei         = (const int*)  d_in[2];
  const int*   node_batch = (const int*)  d_in[3];
  const float* Wf         = (const float*)d_in[4];
  const float* bf         = (const float*)d_in[5];
  const float* Wc         = (const float*)d_in[6];
  const float* bc         = (const float*)d_in[7];
  const float* Wd         = (const float*)d_in[8];
  const float* bd         = (const float*)d_in[9];
  float* out = (float*)d_out;

  // workspace layout (floats)
  float* ws   = (float*)d_ws;
  float* t    = ws;                               // 4,194,304
  float* aggT = t + (size_t)NNODES * BATCH;       // 16,384  ([j][b])
  float* deg  = aggT + HDIM * BATCH;              // 65,536
  int*   cnt  = (int*)(deg + NNODES);             // 64
  float* u    = (float*)(cnt + 64);               // 65,536
  float* v    = u + NNODES;                       // 65,536
  float* dis  = v + NNODES;                       // 65,536
  float* wbuf = dis + NNODES;                     // 262,144
  float* part = wbuf + NEDGES;                    // NSLAB*16,384 = 131,072
  float* xg   = part + (size_t)NSLAB * HDIM * BATCH; // N*H = 16,777,216 (67 MB)

  // zero t | aggT | deg | cnt (contiguous) and the partial slabs
  (void)hipMemsetAsync(t, 0,
      ((size_t)NNODES * BATCH + HDIM * BATCH + NNODES + 64) * sizeof(float),
      stream);
  (void)hipMemsetAsync(part, 0, (size_t)NSLAB * HDIM * BATCH * sizeof(float), stream);

  k_uv    <<<NNODES / 4,   256,  0, stream>>>(hidden, node_idx, Wf, u, v, xg);
  k_edge_w<<<NEDGES / 256, 256,  0, stream>>>(ei, u, v, bf, wbuf, deg);
  k_dis   <<<NNODES / 256, 256,  0, stream>>>(node_batch, deg, dis, t);
  k_cnt   <<<1,            64,   0, stream>>>(node_batch, cnt);
  k_t     <<<NEDGES / 256, 256,  0, stream>>>(ei, node_batch, wbuf, dis, t);
  k_gemm  <<<NNODES / NPB, 1024, 0, stream>>>(xg, t, part);
  k_reduce<<<HDIM * BATCH / 256, 256, 0, stream>>>(part, aggT);
  k_final <<<BATCH,        256,  0, stream>>>(aggT, cnt, Wc, bc, Wd, bd, out);
}